// Round 9
// baseline (1608.178 us; speedup 1.0000x reference)
//
#include <hip/hip_runtime.h>

// RRF2d: y[b,o,p] = sum_l patches[b,l,p] * W[o,l,p] + bias[o,p]
// B=32, C_IN=32, H=W=64, K=3 pad=1, C_OUT=64, L=4096, KL=288
//
// R9 = R4 skeleton (163us, known-good codegen) with two LDS-pipe cuts:
//  (a) halo taps via 2 clamped ALIGNED dword loads (no ds_bpermute at all)
//  (b) weights as o-interleaved float4 in LDS -> one ds_read_b128 per
//      (dh,dw); interleave done by per-lane SOURCE address permutation in
//      global_load_lds (LDS dest stays linear), read side matches.
// Block (64,4): 4 waves x 8 batches = all 32 b => weights leave HBM once.
// Thread tile: 2 cols (float2) x 2 o x 8 b. Grid 32 x 32 = 1024 = 4/CU.
// Staging: CC=1, 36 pieces of 64 floats, 9/wave, vmcnt(9) -> s_barrier.
// LDS 2 x 9 KB = 18 KB.

#define C_IN   32
#define H_SZ   64
#define W_SZ   64
#define C_OUT  64
#define L_SZ   4096
#define KL     288
#define XCH    (H_SZ * W_SZ)
#define WBUF   (9 * 256)            // 2304 floats = 9 KB per buffer

__device__ __forceinline__ void gload_lds4(const float* g, float* l) {
    __builtin_amdgcn_global_load_lds(
        (const __attribute__((address_space(1))) void*)g,
        (__attribute__((address_space(3))) void*)l, 4, 0, 0);
}

__global__ __launch_bounds__(256, 4)
void rrf2d_kernel(const float* __restrict__ x,
                  const float* __restrict__ wgt,
                  const float* __restrict__ bias,
                  float* __restrict__ out) {
    __shared__ float wlds[2][WBUF];      // 18 KB

    const int t   = threadIdx.x;                                  // 0..63
    const int wyu = __builtin_amdgcn_readfirstlane(threadIdx.y);  // 0..3
    const int rb  = t >> 5;
    const int k   = t & 31;
    const int c0  = k * 2;
    const int h0  = blockIdx.x * 2;
    const int o0  = blockIdx.y * 2;
    const int b0  = wyu * 8;
    const int h   = h0 + rb;
    const int p   = h * W_SZ + c0;
    const int p0  = h0 * W_SZ;

    // per-dh clamped tap rows + validity
    int roff[3]; float rvm[3];
    #pragma unroll
    for (int dh = 0; dh < 3; ++dh) {
        const int r = h + dh - 1;
        rvm[dh] = ((unsigned)r < (unsigned)H_SZ) ? 1.f : 0.f;
        const int rc = r < 0 ? 0 : (r > H_SZ - 1 ? H_SZ - 1 : r);
        roff[dh] = rc * W_SZ;
    }
    const bool edgeblk = (h0 == 0) || (h0 == H_SZ - 2);
    const bool lval = (k != 0), rval = (k != 31);
    const int  c0m1 = lval ? c0 - 1 : 0;      // clamped halo cols (values masked)
    const int  c0p2 = rval ? c0 + 2 : W_SZ - 1;

    float2 acc[8][2];
    #pragma unroll
    for (int i = 0; i < 8; ++i)
        #pragma unroll
        for (int j = 0; j < 2; ++j) { acc[i][j].x = 0.f; acc[i][j].y = 0.f; }

    const size_t ostr  = (size_t)KL * L_SZ;
    const size_t base0 = (size_t)o0 * ostr + p0;

    // Per-lane source permutation for o-interleaved float4 LDS layout.
    // LDS entry e = q*64 + lane (piece q), maps to:
    //   float4 f = e>>2 (= lane's own p-pair when read), comp = e&3,
    //   o = (lane>>1)&1, dp = lane&1, p_off = 32*q + 2*(lane>>2) + (lane&1).
    const size_t loff = (size_t)((t >> 1) & 1) * ostr + 2 * (t >> 2) + (t & 1);

    // stage channel c into wlds[c&1]: 36 pieces of 64 floats, 9 per wave.
    // piece r = wyu*9+s: j = r>>2 (tap), q = r&3 (quarter of the 256 floats).
    auto stage = [&](int c) {
        float* dst = wlds[c & 1];
        const size_t coff = (size_t)c * 9 * L_SZ;
        #pragma unroll
        for (int s = 0; s < 9; ++s) {
            const int r = wyu * 9 + s;
            const int j = r >> 2, q = r & 3;
            const float* g = wgt + base0 + coff + (size_t)j * L_SZ + q * 32 + loff;
            gload_lds4(g, dst + j * 256 + q * 64);
        }
    };

    // prologue
    stage(0);
    asm volatile("s_waitcnt vmcnt(0)" ::: "memory");
    __builtin_amdgcn_s_barrier();

    for (int c = 0; c < C_IN; ++c) {
        if (c + 1 < C_IN) {
            stage(c + 1);
            asm volatile("s_waitcnt vmcnt(9)" ::: "memory");
        } else {
            asm volatile("s_waitcnt vmcnt(0)" ::: "memory");
        }
        __builtin_amdgcn_s_barrier();

        const float* wb  = wlds[c & 1];
        const float* xco = x + (size_t)c * XCH;

        #pragma unroll
        for (int dh = 0; dh < 3; ++dh) {
            // weights: one ds_read_b128 per dw; lane t's float4 =
            // {W[o0][p], W[o0][p+1], W[o1][p], W[o1][p+1]} at its own cols
            float4 wq[3];
            #pragma unroll
            for (int dw = 0; dw < 3; ++dw)
                wq[dw] = *(const float4*)(wb + (dh * 3 + dw) * 256 + t * 4);

            // x taps: aligned float2 + 2 clamped aligned dwords (no shuffles)
            float xs[8][4];
            #pragma unroll
            for (int i = 0; i < 8; ++i) {
                const float* xr_ = xco + (size_t)(b0 + i) * (C_IN * XCH) + roff[dh];
                const float2 v  = *(const float2*)(xr_ + c0);
                const float  xl = xr_[c0m1];
                const float  xr = xr_[c0p2];
                float s0 = lval ? xl : 0.f;
                float s1 = v.x;
                float s2 = v.y;
                float s3 = rval ? xr : 0.f;
                if (edgeblk) {                       // block-uniform branch
                    s0 *= rvm[dh]; s1 *= rvm[dh];
                    s2 *= rvm[dh]; s3 *= rvm[dh];
                }
                xs[i][0] = s0; xs[i][1] = s1; xs[i][2] = s2; xs[i][3] = s3;
            }

            // 8b x 3dw x 2o x 2col = 96 FMAs
            #pragma unroll
            for (int i = 0; i < 8; ++i)
                #pragma unroll
                for (int dw = 0; dw < 3; ++dw) {
                    acc[i][0].x = fmaf(xs[i][dw],     wq[dw].x, acc[i][0].x);
                    acc[i][0].y = fmaf(xs[i][dw + 1], wq[dw].y, acc[i][0].y);
                    acc[i][1].x = fmaf(xs[i][dw],     wq[dw].z, acc[i][1].x);
                    acc[i][1].y = fmaf(xs[i][dw + 1], wq[dw].w, acc[i][1].y);
                }
        }
        __builtin_amdgcn_s_barrier();   // wlds[c&1] reads done before overwrite
    }

    #pragma unroll
    for (int j = 0; j < 2; ++j) {
        const float2 bv = *(const float2*)(bias + (size_t)(o0 + j) * L_SZ + p);
        #pragma unroll
        for (int i = 0; i < 8; ++i) {
            float2 r;
            r.x = acc[i][j].x + bv.x;
            r.y = acc[i][j].y + bv.y;
            *(float2*)(out + ((size_t)(b0 + i) * C_OUT + (o0 + j)) * L_SZ + p) = r;
        }
    }
}

extern "C" void kernel_launch(void* const* d_in, const int* in_sizes, int n_in,
                              void* d_out, int out_size, void* d_ws, size_t ws_size,
                              hipStream_t stream) {
    const float* x    = (const float*)d_in[0];
    const float* wgt  = (const float*)d_in[1];
    const float* bias = (const float*)d_in[2];
    float* out        = (float*)d_out;

    dim3 block(64, 4);                    // 4 waves = 4 b-chunks of 8
    dim3 grid(H_SZ / 2, C_OUT / 2);       // 1024 blocks = 4/CU

    hipLaunchKernelGGL(rrf2d_kernel, grid, block, 0, stream, x, wgt, bias, out);
}

// Round 10
// 162.972 us; speedup vs baseline: 9.8678x; 9.8678x over previous
//
#include <hip/hip_runtime.h>

// RRF2d: y[b,o,p] = sum_l patches[b,l,p] * W[o,l,p] + bias[o,p]
// B=32, C_IN=32, H=W=64, K=3 pad=1, C_OUT=64, L=4096, KL=288
//
// R10 = R4 (163us, known-good codegen) with EXACTLY ONE change:
// halo cross-lane moves use DPP wave_shr:1 / wave_shl:1 (VALU pipe)
// instead of __shfl (ds_bpermute, LDS pipe). R4 was LDS-pipe-bound with
// ~78% of LDS cycles in bpermutes; everything else is verbatim R4.
// Block (64,4): 4 waves x 8 batches = all 32 b => weights leave HBM once.
// Thread tile: 2 cols (float2) x 2 o x 8 b. Grid 32 x 32 = 1024 = 4/CU.
// Staging: CC=1, 36 pieces of 64 floats, 9/wave, vmcnt(9) -> s_barrier.

#define C_IN   32
#define H_SZ   64
#define W_SZ   64
#define C_OUT  64
#define L_SZ   4096
#define KL     288
#define XCH    (H_SZ * W_SZ)

__device__ __forceinline__ void gload_lds4(const float* g, float* l) {
    __builtin_amdgcn_global_load_lds(
        (const __attribute__((address_space(1))) void*)g,
        (__attribute__((address_space(3))) void*)l, 4, 0, 0);
}

// lane i <- lane i-1 (wave_shr:1). Lane 0 keeps own value (masked by caller).
__device__ __forceinline__ float dpp_shr1(float v) {
    int i = __builtin_bit_cast(int, v);
    int r = __builtin_amdgcn_update_dpp(i, i, 0x138, 0xF, 0xF, false);
    return __builtin_bit_cast(float, r);
}
// lane i <- lane i+1 (wave_shl:1). Lane 63 keeps own value (masked by caller).
__device__ __forceinline__ float dpp_shl1(float v) {
    int i = __builtin_bit_cast(int, v);
    int r = __builtin_amdgcn_update_dpp(i, i, 0x130, 0xF, 0xF, false);
    return __builtin_bit_cast(float, r);
}

__global__ __launch_bounds__(256, 4)
void rrf2d_kernel(const float* __restrict__ x,
                  const float* __restrict__ wgt,
                  const float* __restrict__ bias,
                  float* __restrict__ out) {
    __shared__ float wlds[2][9 * 2 * 128];   // [buf][(j*2+o)*128 + p_local]

    const int t   = threadIdx.x;                                  // 0..63
    const int wyu = __builtin_amdgcn_readfirstlane(threadIdx.y);  // 0..3
    const int rb  = t >> 5;
    const int k   = t & 31;
    const int c0  = k * 2;
    const int h0  = blockIdx.x * 2;
    const int o0  = blockIdx.y * 2;
    const int b0  = wyu * 8;
    const int h   = h0 + rb;
    const int p   = h * W_SZ + c0;
    const int pl  = rb * 64 + c0;            // p_local (0..127)
    const int p0  = h0 * W_SZ;

    int roff[3]; float rvm[3];
    #pragma unroll
    for (int dh = 0; dh < 3; ++dh) {
        const int r = h + dh - 1;
        rvm[dh] = ((unsigned)r < (unsigned)H_SZ) ? 1.f : 0.f;
        const int rc = r < 0 ? 0 : (r > H_SZ - 1 ? H_SZ - 1 : r);
        roff[dh] = rc * W_SZ + c0;
    }
    const bool lval = (k != 0), rval = (k != 31);

    float2 acc[8][2];
    #pragma unroll
    for (int i = 0; i < 8; ++i)
        #pragma unroll
        for (int j = 0; j < 2; ++j) { acc[i][j].x = 0.f; acc[i][j].y = 0.f; }

    const size_t obase[2] = { (size_t)o0 * (KL * (size_t)L_SZ) + p0,
                              (size_t)(o0 + 1) * (KL * (size_t)L_SZ) + p0 };

    // stage weights for channel cc into wlds[cc&1]: 9 DMA pieces per wave
    auto stage = [&](int cc) {
        float* dst = wlds[cc & 1];
        const size_t coff = (size_t)cc * 9 * L_SZ;
        #pragma unroll
        for (int s = 0; s < 9; ++s) {
            const int r = wyu * 9 + s;
            const int j = r >> 2, o = (r >> 1) & 1, q = r & 1;
            const float* g = wgt + obase[o] + coff + (size_t)j * L_SZ + q * 64 + t;
            gload_lds4(g, dst + (j * 2 + o) * 128 + q * 64);
        }
    };

    // prologue
    stage(0);
    asm volatile("s_waitcnt vmcnt(0)" ::: "memory");
    __builtin_amdgcn_s_barrier();

    for (int c = 0; c < C_IN; ++c) {
        if (c + 1 < C_IN) {
            stage(c + 1);
            asm volatile("s_waitcnt vmcnt(9)" ::: "memory");
        } else {
            asm volatile("s_waitcnt vmcnt(0)" ::: "memory");
        }
        __builtin_amdgcn_s_barrier();

        const float* wb  = wlds[c & 1];
        const float* xco = x + (size_t)c * XCH;

        #pragma unroll
        for (int dh = 0; dh < 3; ++dh) {
            float2 wv[3][2];
            #pragma unroll
            for (int dw = 0; dw < 3; ++dw) {
                const int j = dh * 3 + dw;
                wv[dw][0] = *(const float2*)(wb + (j * 2 + 0) * 128 + pl);
                wv[dw][1] = *(const float2*)(wb + (j * 2 + 1) * 128 + pl);
            }

            float xs[8][4];
            #pragma unroll
            for (int i = 0; i < 8; ++i) {
                const float* xr_ = xco + ((size_t)(b0 + i) * C_IN) * XCH + roff[dh];
                float2 v = *(const float2*)xr_;
                v.x *= rvm[dh];
                v.y *= rvm[dh];
                const float xl = dpp_shr1(v.y);   // lane t-1's v.y  (col c0-1)
                const float xr = dpp_shl1(v.x);   // lane t+1's v.x  (col c0+2)
                xs[i][0] = lval ? xl : 0.f;
                xs[i][1] = v.x;
                xs[i][2] = v.y;
                xs[i][3] = rval ? xr : 0.f;
            }

            #pragma unroll
            for (int i = 0; i < 8; ++i)
                #pragma unroll
                for (int dw = 0; dw < 3; ++dw) {
                    acc[i][0].x = fmaf(xs[i][dw],     wv[dw][0].x, acc[i][0].x);
                    acc[i][0].y = fmaf(xs[i][dw + 1], wv[dw][0].y, acc[i][0].y);
                    acc[i][1].x = fmaf(xs[i][dw],     wv[dw][1].x, acc[i][1].x);
                    acc[i][1].y = fmaf(xs[i][dw + 1], wv[dw][1].y, acc[i][1].y);
                }
        }
        __builtin_amdgcn_s_barrier();   // reads of wlds[c&1] done before overwrite
    }

    #pragma unroll
    for (int j = 0; j < 2; ++j) {
        const float2 bv = *(const float2*)(bias + (size_t)(o0 + j) * L_SZ + p);
        #pragma unroll
        for (int i = 0; i < 8; ++i) {
            float2 r;
            r.x = acc[i][j].x + bv.x;
            r.y = acc[i][j].y + bv.y;
            *(float2*)(out + ((size_t)(b0 + i) * C_OUT + (o0 + j)) * L_SZ + p) = r;
        }
    }
}

extern "C" void kernel_launch(void* const* d_in, const int* in_sizes, int n_in,
                              void* d_out, int out_size, void* d_ws, size_t ws_size,
                              hipStream_t stream) {
    const float* x    = (const float*)d_in[0];
    const float* wgt  = (const float*)d_in[1];
    const float* bias = (const float*)d_in[2];
    float* out        = (float*)d_out;

    dim3 block(64, 4);                    // 4 waves = 4 b-chunks of 8
    dim3 grid(H_SZ / 2, C_OUT / 2);       // 1024 blocks = 4/CU

    hipLaunchKernelGGL(rrf2d_kernel, grid, block, 0, stream, x, wgt, bias, out);
}